// Round 2
// baseline (155.007 us; speedup 1.0000x reference)
//
#include <hip/hip_runtime.h>
#include <float.h>

// Chamfer distance, two-pass:
//  pass 1: per (dir, batch, query-chunk, target-slice) block computes
//          partial min_m (||t||^2 - 2 q.t) + ||q||^2 over a 1024-target slice,
//          8 queries/thread (4 packed float2), broadcast targets from LDS.
//  pass 2: min over 4 slices, global sum, atomicAdd scaled.
// B=32, N=M=4096, C=3, fp32.

#define BLK    256
#define QPT    8        // queries per thread
#define NP     4        // float2 packs per thread
#define SLICES 4        // target-dim split
#define MSL    1024     // targets per slice (M / SLICES)

typedef float f2 __attribute__((ext_vector_type(2)));

struct __align__(16) F4 { float x, y, z, s; };

__global__ __launch_bounds__(BLK)
void chamfer_partial(const float* __restrict__ x,
                     const float* __restrict__ recon,
                     float* __restrict__ ws,
                     int B, int N, int M)
{
    const int dir = blockIdx.y;                  // 0: q=x,t=recon ; 1: q=recon,t=x
    const float* q = (dir == 0) ? x : recon;
    const float* t = (dir == 0) ? recon : x;

    const int qpb    = BLK * QPT;                // 2048 queries per block
    const int chunks = N / qpb;                  // 2
    const int slice  = blockIdx.x % SLICES;
    const int rem    = blockIdx.x / SLICES;
    const int chunk  = rem % chunks;
    const int b      = rem / chunks;
    const int tid    = threadIdx.x;

    __shared__ F4 lds[MSL];                      // 16 KiB

    // Stage this slice's targets (coalesced flat copy of 3*MSL floats).
    const float* src = t + ((size_t)b * M + (size_t)slice * MSL) * 3;
    for (int e = tid; e < MSL * 3; e += BLK) {
        int m = e / 3, c = e - 3 * m;
        ((float*)&lds[m])[c] = src[e];
    }
    __syncthreads();
    for (int m = tid; m < MSL; m += BLK) {
        F4 p = lds[m];
        lds[m].s = p.x * p.x + p.y * p.y + p.z * p.z;
    }
    __syncthreads();

    // Load 8 query points as 4 float2 packs; precompute -2q and ||q||^2.
    f2 nqx[NP], nqy[NP], nqz[NP], q2[NP], mn[NP];
    #pragma unroll
    for (int i = 0; i < NP; ++i) {
        int n0 = chunk * qpb + (2 * i) * BLK + tid;          // pack lo
        const float* qp0 = q + ((size_t)b * N + n0) * 3;
        const float* qp1 = qp0 + 3 * BLK;                    // pack hi (n0+BLK)
        f2 ax = { qp0[0], qp1[0] };
        f2 ay = { qp0[1], qp1[1] };
        f2 az = { qp0[2], qp1[2] };
        nqx[i] = -2.0f * ax;
        nqy[i] = -2.0f * ay;
        nqz[i] = -2.0f * az;
        q2[i]  = ax * ax + ay * ay + az * az;
        mn[i]  = (f2)(FLT_MAX);
    }

    // Main loop: 1 broadcast ds_read_b128 amortized over 8 queries,
    // packed fp32 fma/min (v_pk_fma_f32 where available).
    #pragma unroll 4
    for (int m = 0; m < MSL; ++m) {
        F4 p = lds[m];
        f2 px = (f2)(p.x), py = (f2)(p.y), pz = (f2)(p.z), ps = (f2)(p.s);
        #pragma unroll
        for (int i = 0; i < NP; ++i) {
            f2 d = __builtin_elementwise_fma(nqx[i], px, ps);
            d = __builtin_elementwise_fma(nqy[i], py, d);
            d = __builtin_elementwise_fma(nqz[i], pz, d);
            mn[i] = __builtin_elementwise_min(mn[i], d);
        }
    }

    // Write partial (min + ||q||^2), layout ws[slice][dir][b][n] — coalesced.
    size_t wbase = (size_t)slice * (2 * (size_t)B * N)
                 + ((size_t)dir * B + b) * (size_t)N;
    #pragma unroll
    for (int i = 0; i < NP; ++i) {
        f2 r = mn[i] + q2[i];
        int n0 = chunk * qpb + (2 * i) * BLK + tid;
        ws[wbase + n0]       = r.x;
        ws[wbase + n0 + BLK] = r.y;
    }
}

__global__ __launch_bounds__(BLK)
void chamfer_reduce(const float* __restrict__ ws,
                    float* __restrict__ out,
                    float scale)
{
    const size_t Q = 2u * 32u * 4096u;           // 262144 queries (both dirs)
    int t = blockIdx.x * BLK + threadIdx.x;

    float v = ws[t];
    v = fminf(v, ws[Q + t]);
    v = fminf(v, ws[2 * Q + t]);
    v = fminf(v, ws[3 * Q + t]);

    #pragma unroll
    for (int off = 32; off > 0; off >>= 1)
        v += __shfl_down(v, off, 64);

    __shared__ float red[BLK / 64];
    int tid = threadIdx.x;
    if ((tid & 63) == 0) red[tid >> 6] = v;
    __syncthreads();
    if (tid == 0) {
        float s = 0.0f;
        #pragma unroll
        for (int w = 0; w < BLK / 64; ++w) s += red[w];
        atomicAdd(out, s * scale);
    }
}

extern "C" void kernel_launch(void* const* d_in, const int* in_sizes, int n_in,
                              void* d_out, int out_size, void* d_ws, size_t ws_size,
                              hipStream_t stream) {
    const float* x     = (const float*)d_in[0];
    const float* recon = (const float*)d_in[1];
    float* out = (float*)d_out;
    float* ws  = (float*)d_ws;                   // needs 4 MiB

    const int B = 32, N = 4096, M = 4096;
    const float scale = 1.0f / ((float)B * (float)N);   // N == M

    hipMemsetAsync(out, 0, sizeof(float), stream);

    dim3 grid1(B * (N / (BLK * QPT)) * SLICES, 2);      // (256, 2) = 512 blocks
    chamfer_partial<<<grid1, BLK, 0, stream>>>(x, recon, ws, B, N, M);

    dim3 grid2((2 * B * N) / BLK);                      // 1024 blocks
    chamfer_reduce<<<grid2, BLK, 0, stream>>>(ws, out, scale);
}